// Round 1
// 143.163 us; speedup vs baseline: 1.0015x; 1.0015x over previous
//
#include <hip/hip_runtime.h>

#define T_SEQ 2048
#define C_DIM 1024
#define H_DIM 64
#define B_DIM 8
#define NROW (B_DIM * T_SEQ)  // 16384

typedef __attribute__((ext_vector_type(8))) short short8;
typedef __attribute__((ext_vector_type(4))) float f32x4;

__device__ __forceinline__ short f2bf(float f) {
  unsigned u = __builtin_bit_cast(unsigned, f);
  u += 0x7fffu + ((u >> 16) & 1u);  // round-to-nearest-even
  return (short)(u >> 16);
}

// ---------------------------------------------------------------------------
// P: Wt2 in FRAGMENT-LINEAR order: unit (kc, ntg, kh, lane) of 8 shorts holds
// W_mat[k = kc*128 + kh*32 + (lane>>4)*8 + e][hcol = (ntg&3)*16 + (lane&15)]
// with mat = ntg>>2.  This is byte-for-byte the B fragment each lane feeds to
// mfma_f32_16x16x32_bf16, so qkv_gemm loads B global->VGPR directly (no LDS).
// 24576 units = 384 KB.  Grid 96 x 256 = one unit per thread.
// ---------------------------------------------------------------------------
__global__ __launch_bounds__(256) void w_prep(
    const float* __restrict__ Wq, const float* __restrict__ Wk,
    const float* __restrict__ Wv, short* __restrict__ Wt2) {
  const int unit = blockIdx.x * 256 + threadIdx.x;  // 0..24575
  const int lane = unit & 63;
  const int t = unit >> 6;
  const int kh = t & 3;
  const int g = t >> 2;    // kc*12 + ntg
  const int ntg = g % 12;
  const int kc = g / 12;
  const int n16 = lane & 15, quad = lane >> 4;
  const int mat = ntg >> 2;
  const int h = (ntg & 3) * 16 + n16;
  const int kb = kc * 128 + kh * 32 + quad * 8;
  const float* W = (mat == 0) ? Wq : (mat == 1 ? Wk : Wv);
  short8 v;
#pragma unroll
  for (int e = 0; e < 8; ++e) v[e] = f2bf(W[(size_t)(kb + e) * H_DIM + h]);
  *(short8*)(Wt2 + (size_t)unit * 8) = v;
}

// LDS address (in shorts) for A frag unit (tile, kh, quad, n16); XOR-swizzled
// low 16B-unit index keeps both staging writes and frag reads conflict-free.
__device__ __forceinline__ int lds_addr(int tile, int kh, int qd, int nn) {
  return tile * 2048 + kh * 512 + (qd * 16 + (nn ^ ((kh * 4 + qd) & 7))) * 8;
}

// ---------------------------------------------------------------------------
// K1: QKV projection.  512 blocks (BM=32) x 256 thr, BN=192, BK=128, 8 iters.
// B fragments load global->VGPR straight from fragment-linear Wt2 (L2-hot,
// 1 chunk ahead).  Only A (fp32 x, shared by all 4 waves) goes through LDS:
// 2 x 8 KB double buffer, reg-staged 2 chunks ahead (HBM latency window).
// ONE raw s_barrier per iter with lgkmcnt(0) only -- vmcnt is NEVER drained,
// so prefetch loads stay in flight across barriers (counted waits are left to
// the compiler's per-register tracking; global loads land in private VGPRs so
// no cross-wave vmem hazard exists).  LDS 16 KB -> 2-3 blocks/CU.
// ---------------------------------------------------------------------------
__global__ __launch_bounds__(256, 2) void qkv_gemm(
    const float* __restrict__ x, const short* __restrict__ Wt2,
    short* __restrict__ q, short* __restrict__ k, short* __restrict__ vt) {
  __shared__ __align__(16) short As[2][4096];  // 2 x 8 KB (32 x 128 bf16)
  const int tid = threadIdx.x;
  const int w = tid >> 6, lane = tid & 63;
  const int n16 = lane & 15, quad = lane >> 4;
  const int row0 = blockIdx.x * 32;

  f32x4 acc[2][3];
#pragma unroll
  for (int mt = 0; mt < 2; ++mt)
#pragma unroll
    for (int ln = 0; ln < 3; ++ln) acc[mt][ln] = (f32x4){0.f, 0.f, 0.f, 0.f};

  // A staging geometry: thread covers two 8-float groups (u2 = i*256+tid).
  const int u20 = tid, u21 = 256 + tid;
  const int sr0 = u20 >> 4, f0 = u20 & 15;
  const int sr1 = u21 >> 4, f1 = u21 & 15;
  const float* ap0 = x + (size_t)(row0 + sr0) * C_DIM + f0 * 8;
  const float* ap1 = x + (size_t)(row0 + sr1) * C_DIM + f1 * 8;
  const int soff0 = lds_addr(sr0 >> 4, f0 >> 2, f0 & 3, sr0 & 15);
  const int soff1 = lds_addr(sr1 >> 4, f1 >> 2, f1 & 3, sr1 & 15);

  // A frag read swizzle per kh (tile/kh offsets added statically below)
  int swz[4];
#pragma unroll
  for (int kh = 0; kh < 4; ++kh)
    swz[kh] = (quad * 16 + (n16 ^ ((kh * 4 + quad) & 7))) * 8;

  // B fragment base for this wave (cols [w*48, w*48+48))
  const short* bbase = Wt2 + (size_t)(w * 3) * 2048 + (size_t)lane * 8;

  float4 astg[2][4];  // [parity][4 x float4] -- statically indexed (unrolled)
  short8 bfr[12];     // [ln*4+kh]

#define STAGE_A(d, p)                                      \
  {                                                        \
    short8 av0, av1;                                       \
    _Pragma("unroll") for (int e = 0; e < 4; ++e) {        \
      av0[e] = f2bf(((const float*)&astg[d][0])[e]);       \
      av0[e + 4] = f2bf(((const float*)&astg[d][1])[e]);   \
      av1[e] = f2bf(((const float*)&astg[d][2])[e]);       \
      av1[e + 4] = f2bf(((const float*)&astg[d][3])[e]);   \
    }                                                      \
    *(short8*)(&As[p][0] + soff0) = av0;                   \
    *(short8*)(&As[p][0] + soff1) = av1;                   \
  }

  // ---- prologue: issue A(0), A(1), B(0); stage A(0) ----
  astg[0][0] = *(const float4*)(ap0);
  astg[0][1] = *(const float4*)(ap0 + 4);
  astg[0][2] = *(const float4*)(ap1);
  astg[0][3] = *(const float4*)(ap1 + 4);
  astg[1][0] = *(const float4*)(ap0 + 128);
  astg[1][1] = *(const float4*)(ap0 + 132);
  astg[1][2] = *(const float4*)(ap1 + 128);
  astg[1][3] = *(const float4*)(ap1 + 132);
#pragma unroll
  for (int ln = 0; ln < 3; ++ln)
#pragma unroll
    for (int kh = 0; kh < 4; ++kh)
      bfr[ln * 4 + kh] = *(const short8*)(bbase + ln * 2048 + kh * 512);
  STAGE_A(0, 0);  // compiler waits vmcnt only for astg[0] (oldest 4 loads)
  asm volatile("s_waitcnt lgkmcnt(0)" ::: "memory");
  __builtin_amdgcn_sched_barrier(0);
  __builtin_amdgcn_s_barrier();
  __builtin_amdgcn_sched_barrier(0);

  // ---- main loop: compute chunk kc; prefetch B(kc+1), A(kc+2); stage A(kc+1)
#pragma unroll
  for (int kc = 0; kc < 8; ++kc) {
    const short* asb = &As[kc & 1][0];
#pragma unroll
    for (int kh = 0; kh < 4; ++kh) {
      const short8 a0 = *(const short8*)(asb + kh * 512 + swz[kh]);
      const short8 a1 = *(const short8*)(asb + 2048 + kh * 512 + swz[kh]);
#pragma unroll
      for (int ln = 0; ln < 3; ++ln) {
        acc[0][ln] = __builtin_amdgcn_mfma_f32_16x16x32_bf16(
            a0, bfr[ln * 4 + kh], acc[0][ln], 0, 0, 0);
        acc[1][ln] = __builtin_amdgcn_mfma_f32_16x16x32_bf16(
            a1, bfr[ln * 4 + kh], acc[1][ln], 0, 0, 0);
      }
    }
    if (kc < 7) {
      // B(kc+1): 12 coalesced 16B loads from L2-resident Wt2 (1-iter window)
      const short* bc = bbase + (size_t)(kc + 1) * 24576;
#pragma unroll
      for (int ln = 0; ln < 3; ++ln)
#pragma unroll
        for (int kh = 0; kh < 4; ++kh)
          bfr[ln * 4 + kh] = *(const short8*)(bc + ln * 2048 + kh * 512);
      if (kc < 6) {
        // A(kc+2): HBM loads, 2-iter window before staging consumes them
        astg[kc & 1][0] = *(const float4*)(ap0 + (kc + 2) * 128);
        astg[kc & 1][1] = *(const float4*)(ap0 + (kc + 2) * 128 + 4);
        astg[kc & 1][2] = *(const float4*)(ap1 + (kc + 2) * 128);
        astg[kc & 1][3] = *(const float4*)(ap1 + (kc + 2) * 128 + 4);
      }
      // stage A(kc+1) into the buffer the OTHER waves finished reading at the
      // previous barrier; compiler waits vmcnt for its 4 (old) loads only
      STAGE_A((kc + 1) & 1, (kc + 1) & 1);
      asm volatile("s_waitcnt lgkmcnt(0)" ::: "memory");
      __builtin_amdgcn_sched_barrier(0);
      __builtin_amdgcn_s_barrier();
      __builtin_amdgcn_sched_barrier(0);
    }
  }
#undef STAGE_A

  // ---- epilogue (unchanged) ----
  const int b = row0 >> 11;
#pragma unroll
  for (int mt = 0; mt < 2; ++mt)
#pragma unroll
    for (int ln = 0; ln < 3; ++ln) {
      const int ntg = w * 3 + ln;
      const int mat = ntg >> 2;             // wave-uniform per frag
      const int cl = (ntg & 3) * 16 + n16;  // column within matrix
#pragma unroll
      for (int r = 0; r < 4; ++r) {
        const int row = row0 + mt * 16 + quad * 4 + r;
        const float v = acc[mt][ln][r];
        if (mat == 0)
          q[(size_t)row * H_DIM + cl] = f2bf(v * 0.125f);
        else if (mat == 1)
          k[(size_t)row * H_DIM + cl] = f2bf(v);
        else
          vt[((size_t)b * H_DIM + cl) * T_SEQ + (row & (T_SEQ - 1))] = f2bf(v);
      }
    }
}

// ---------------------------------------------------------------------------
// K2: MFMA flash attention (byte-identical to previous round -- clean A/B on
// the qkv restructure; if total time doesn't move, THIS is the ~40us kernel).
// ---------------------------------------------------------------------------
__global__ __launch_bounds__(256) void attn_mfma(
    const short* __restrict__ q, const short* __restrict__ k,
    const short* __restrict__ vt, float* __restrict__ out) {
  __shared__ __align__(16) short pbuf[4][1024];
  __shared__ __align__(16) float oshare[3][1024];
  __shared__ __align__(16) float lshare[3][256];
  const int tid = threadIdx.x;
  const int w = tid >> 6;
  const int lane = tid & 63;
  const int n16 = lane & 15, quad = lane >> 4;
  const int b = blockIdx.x & 7;
  const int qt = (T_SEQ / 16 - 1) - (blockIdx.x >> 3);  // heavy blocks first
  const int r0 = qt * 16;

  const short* qb = q + ((size_t)b * T_SEQ + r0) * H_DIM;
  const short* kb = k + (size_t)b * T_SEQ * H_DIM;
  const short* vb = vt + (size_t)b * H_DIM * T_SEQ;

  const short8 aq0 = *(const short8*)(qb + (size_t)n16 * H_DIM + quad * 8);
  const short8 aq1 = *(const short8*)(qb + (size_t)n16 * H_DIM + 32 + quad * 8);

  f32x4 O[4];
#pragma unroll
  for (int i = 0; i < 4; ++i) O[i] = (f32x4){0.f, 0.f, 0.f, 0.f};
  float lsum[4] = {0.f, 0.f, 0.f, 0.f};

  const int nj = (r0 + 16 + 63) >> 6;  // j-tiles of 64
  for (int jt = w; jt < nj; jt += 4) {
    const int j0 = jt * 64;

    short8 bk[4][2];
#pragma unroll
    for (int nt = 0; nt < 4; ++nt) {
      const short* kp = kb + (size_t)(j0 + nt * 16 + n16) * H_DIM + quad * 8;
      bk[nt][0] = *(const short8*)kp;
      bk[nt][1] = *(const short8*)(kp + 32);
    }

    f32x4 s[4];
#pragma unroll
    for (int nt = 0; nt < 4; ++nt) {
      f32x4 z = (f32x4){0.f, 0.f, 0.f, 0.f};
      z = __builtin_amdgcn_mfma_f32_16x16x32_bf16(aq0, bk[nt][0], z, 0, 0, 0);
      z = __builtin_amdgcn_mfma_f32_16x16x32_bf16(aq1, bk[nt][1], z, 0, 0, 0);
      s[nt] = z;
    }

    const bool full = (j0 + 64 <= r0);  // wave-uniform
#pragma unroll
    for (int nt = 0; nt < 4; ++nt) {
      const int base =
          (nt >> 1) * 512 + ((((nt & 1) << 1) | (n16 >> 3)) * 128) + (n16 & 7);
#pragma unroll
      for (int r = 0; r < 4; ++r) {
        float p;
        if (full) {
          p = __expf(s[nt][r]);
        } else {
          const int j = j0 + nt * 16 + n16;
          const int row = r0 + quad * 4 + r;
          p = (j <= row) ? __expf(s[nt][r]) : 0.f;
        }
        lsum[r] += p;
        pbuf[w][base + (quad * 4 + r) * 8] = f2bf(p);
      }
    }

    short8 bv[4][2];
#pragma unroll
    for (int ht = 0; ht < 4; ++ht)
#pragma unroll
      for (int kh = 0; kh < 2; ++kh)
        bv[ht][kh] = *(const short8*)(vb + (size_t)(ht * 16 + n16) * T_SEQ +
                                      j0 + kh * 32 + quad * 8);

    const short8 ap0 = *(const short8*)(&pbuf[w][0] + lane * 8);
    const short8 ap1 = *(const short8*)(&pbuf[w][0] + 512 + lane * 8);

#pragma unroll
    for (int ht = 0; ht < 4; ++ht) {
      O[ht] = __builtin_amdgcn_mfma_f32_16x16x32_bf16(ap0, bv[ht][0], O[ht], 0, 0, 0);
      O[ht] = __builtin_amdgcn_mfma_f32_16x16x32_bf16(ap1, bv[ht][1], O[ht], 0, 0, 0);
    }
  }

  if (w != 0) {
#pragma unroll
    for (int ht = 0; ht < 4; ++ht)
#pragma unroll
      for (int r = 0; r < 4; ++r)
        oshare[w - 1][(ht * 4 + r) * 64 + lane] = O[ht][r];
#pragma unroll
    for (int r = 0; r < 4; ++r) lshare[w - 1][r * 64 + lane] = lsum[r];
  }
  __syncthreads();
  if (w == 0) {
#pragma unroll
    for (int ht = 0; ht < 4; ++ht)
#pragma unroll
      for (int r = 0; r < 4; ++r) {
        float a = O[ht][r];
#pragma unroll
        for (int ow = 0; ow < 3; ++ow) a += oshare[ow][(ht * 4 + r) * 64 + lane];
        O[ht][r] = a;
      }
#pragma unroll
    for (int r = 0; r < 4; ++r) {
      float vsum = lsum[r];
#pragma unroll
      for (int ow = 0; ow < 3; ++ow) vsum += lshare[ow][r * 64 + lane];
      vsum += __shfl_xor(vsum, 1);
      vsum += __shfl_xor(vsum, 2);
      vsum += __shfl_xor(vsum, 4);
      vsum += __shfl_xor(vsum, 8);
      lsum[r] = vsum;
    }
#pragma unroll
    for (int ht = 0; ht < 4; ++ht)
#pragma unroll
      for (int r = 0; r < 4; ++r)
        out[((size_t)b * T_SEQ + r0 + quad * 4 + r) * H_DIM + ht * 16 + n16] =
            O[ht][r] / lsum[r];
  }
}

extern "C" void kernel_launch(void* const* d_in, const int* in_sizes, int n_in,
                              void* d_out, int out_size, void* d_ws,
                              size_t ws_size, hipStream_t stream) {
  const float* x = (const float*)d_in[0];
  const float* Wq = (const float*)d_in[1];
  const float* Wk = (const float*)d_in[2];
  const float* Wv = (const float*)d_in[3];

  char* ws = (char*)d_ws;
  short* Wt = (short*)ws;                       // 384 KB (fragment-linear)
  short* q = (short*)(ws + 3 * 64 * 1024 * 2);  // 2 MB each
  short* kk = (short*)(ws + 3 * 64 * 1024 * 2 + 2097152);
  short* vt = (short*)(ws + 3 * 64 * 1024 * 2 + 2 * 2097152);

  w_prep<<<96, 256, 0, stream>>>(Wq, Wk, Wv, Wt);
  qkv_gemm<<<NROW / 32, 256, 0, stream>>>(x, Wt, q, kk, vt);
  attn_mfma<<<B_DIM * (T_SEQ / 16), 256, 0, stream>>>(q, kk, vt, (float*)d_out);
}

// Round 2
// 136.992 us; speedup vs baseline: 1.0467x; 1.0450x over previous
//
#include <hip/hip_runtime.h>

#define T_SEQ 2048
#define C_DIM 1024
#define H_DIM 64
#define B_DIM 8
#define NROW (B_DIM * T_SEQ)  // 16384

typedef __attribute__((ext_vector_type(8))) short short8;
typedef __attribute__((ext_vector_type(4))) float f32x4;

__device__ __forceinline__ short f2bf(float f) {
  unsigned u = __builtin_bit_cast(unsigned, f);
  u += 0x7fffu + ((u >> 16) & 1u);  // round-to-nearest-even
  return (short)(u >> 16);
}

// ---------------------------------------------------------------------------
// P: Wt2 in FRAGMENT-LINEAR order: unit (kc, ntg, kh, lane) of 8 shorts holds
// W_mat[k = kc*128 + kh*32 + (lane>>4)*8 + e][hcol = (ntg&3)*16 + (lane&15)]
// with mat = ntg>>2.  (unchanged)
// ---------------------------------------------------------------------------
__global__ __launch_bounds__(256) void w_prep(
    const float* __restrict__ Wq, const float* __restrict__ Wk,
    const float* __restrict__ Wv, short* __restrict__ Wt2) {
  const int unit = blockIdx.x * 256 + threadIdx.x;  // 0..24575
  const int lane = unit & 63;
  const int t = unit >> 6;
  const int kh = t & 3;
  const int g = t >> 2;    // kc*12 + ntg
  const int ntg = g % 12;
  const int kc = g / 12;
  const int n16 = lane & 15, quad = lane >> 4;
  const int mat = ntg >> 2;
  const int h = (ntg & 3) * 16 + n16;
  const int kb = kc * 128 + kh * 32 + quad * 8;
  const float* W = (mat == 0) ? Wq : (mat == 1 ? Wk : Wv);
  short8 v;
#pragma unroll
  for (int e = 0; e < 8; ++e) v[e] = f2bf(W[(size_t)(kb + e) * H_DIM + h]);
  *(short8*)(Wt2 + (size_t)unit * 8) = v;
}

// LDS address (in shorts) for A frag unit (tile, kh, quad, n16); XOR-swizzled
// low 16B-unit index keeps both staging writes and frag reads conflict-free.
__device__ __forceinline__ int lds_addr(int tile, int kh, int qd, int nn) {
  return tile * 2048 + kh * 512 + (qd * 16 + (nn ^ ((kh * 4 + qd) & 7))) * 8;
}

// ---------------------------------------------------------------------------
// K1: QKV projection (unchanged from previous round -- neutral vs the old
// 2-barrier structure, i.e. already at its structural bound; kept for the
// smaller 16 KB LDS footprint).
// ---------------------------------------------------------------------------
__global__ __launch_bounds__(256, 2) void qkv_gemm(
    const float* __restrict__ x, const short* __restrict__ Wt2,
    short* __restrict__ q, short* __restrict__ k, short* __restrict__ vt) {
  __shared__ __align__(16) short As[2][4096];  // 2 x 8 KB (32 x 128 bf16)
  const int tid = threadIdx.x;
  const int w = tid >> 6, lane = tid & 63;
  const int n16 = lane & 15, quad = lane >> 4;
  const int row0 = blockIdx.x * 32;

  f32x4 acc[2][3];
#pragma unroll
  for (int mt = 0; mt < 2; ++mt)
#pragma unroll
    for (int ln = 0; ln < 3; ++ln) acc[mt][ln] = (f32x4){0.f, 0.f, 0.f, 0.f};

  const int u20 = tid, u21 = 256 + tid;
  const int sr0 = u20 >> 4, f0 = u20 & 15;
  const int sr1 = u21 >> 4, f1 = u21 & 15;
  const float* ap0 = x + (size_t)(row0 + sr0) * C_DIM + f0 * 8;
  const float* ap1 = x + (size_t)(row0 + sr1) * C_DIM + f1 * 8;
  const int soff0 = lds_addr(sr0 >> 4, f0 >> 2, f0 & 3, sr0 & 15);
  const int soff1 = lds_addr(sr1 >> 4, f1 >> 2, f1 & 3, sr1 & 15);

  int swz[4];
#pragma unroll
  for (int kh = 0; kh < 4; ++kh)
    swz[kh] = (quad * 16 + (n16 ^ ((kh * 4 + quad) & 7))) * 8;

  const short* bbase = Wt2 + (size_t)(w * 3) * 2048 + (size_t)lane * 8;

  float4 astg[2][4];
  short8 bfr[12];

#define STAGE_A(d, p)                                      \
  {                                                        \
    short8 av0, av1;                                       \
    _Pragma("unroll") for (int e = 0; e < 4; ++e) {        \
      av0[e] = f2bf(((const float*)&astg[d][0])[e]);       \
      av0[e + 4] = f2bf(((const float*)&astg[d][1])[e]);   \
      av1[e] = f2bf(((const float*)&astg[d][2])[e]);       \
      av1[e + 4] = f2bf(((const float*)&astg[d][3])[e]);   \
    }                                                      \
    *(short8*)(&As[p][0] + soff0) = av0;                   \
    *(short8*)(&As[p][0] + soff1) = av1;                   \
  }

  astg[0][0] = *(const float4*)(ap0);
  astg[0][1] = *(const float4*)(ap0 + 4);
  astg[0][2] = *(const float4*)(ap1);
  astg[0][3] = *(const float4*)(ap1 + 4);
  astg[1][0] = *(const float4*)(ap0 + 128);
  astg[1][1] = *(const float4*)(ap0 + 132);
  astg[1][2] = *(const float4*)(ap1 + 128);
  astg[1][3] = *(const float4*)(ap1 + 132);
#pragma unroll
  for (int ln = 0; ln < 3; ++ln)
#pragma unroll
    for (int kh = 0; kh < 4; ++kh)
      bfr[ln * 4 + kh] = *(const short8*)(bbase + ln * 2048 + kh * 512);
  STAGE_A(0, 0);
  asm volatile("s_waitcnt lgkmcnt(0)" ::: "memory");
  __builtin_amdgcn_sched_barrier(0);
  __builtin_amdgcn_s_barrier();
  __builtin_amdgcn_sched_barrier(0);

#pragma unroll
  for (int kc = 0; kc < 8; ++kc) {
    const short* asb = &As[kc & 1][0];
#pragma unroll
    for (int kh = 0; kh < 4; ++kh) {
      const short8 a0 = *(const short8*)(asb + kh * 512 + swz[kh]);
      const short8 a1 = *(const short8*)(asb + 2048 + kh * 512 + swz[kh]);
#pragma unroll
      for (int ln = 0; ln < 3; ++ln) {
        acc[0][ln] = __builtin_amdgcn_mfma_f32_16x16x32_bf16(
            a0, bfr[ln * 4 + kh], acc[0][ln], 0, 0, 0);
        acc[1][ln] = __builtin_amdgcn_mfma_f32_16x16x32_bf16(
            a1, bfr[ln * 4 + kh], acc[1][ln], 0, 0, 0);
      }
    }
    if (kc < 7) {
      const short* bc = bbase + (size_t)(kc + 1) * 24576;
#pragma unroll
      for (int ln = 0; ln < 3; ++ln)
#pragma unroll
        for (int kh = 0; kh < 4; ++kh)
          bfr[ln * 4 + kh] = *(const short8*)(bc + ln * 2048 + kh * 512);
      if (kc < 6) {
        astg[kc & 1][0] = *(const float4*)(ap0 + (kc + 2) * 128);
        astg[kc & 1][1] = *(const float4*)(ap0 + (kc + 2) * 128 + 4);
        astg[kc & 1][2] = *(const float4*)(ap1 + (kc + 2) * 128);
        astg[kc & 1][3] = *(const float4*)(ap1 + (kc + 2) * 128 + 4);
      }
      STAGE_A((kc + 1) & 1, (kc + 1) & 1);
      asm volatile("s_waitcnt lgkmcnt(0)" ::: "memory");
      __builtin_amdgcn_sched_barrier(0);
      __builtin_amdgcn_s_barrier();
      __builtin_amdgcn_sched_barrier(0);
    }
  }
#undef STAGE_A

  const int b = row0 >> 11;
#pragma unroll
  for (int mt = 0; mt < 2; ++mt)
#pragma unroll
    for (int ln = 0; ln < 3; ++ln) {
      const int ntg = w * 3 + ln;
      const int mat = ntg >> 2;
      const int cl = (ntg & 3) * 16 + n16;
#pragma unroll
      for (int r = 0; r < 4; ++r) {
        const int row = row0 + mt * 16 + quad * 4 + r;
        const float v = acc[mt][ln][r];
        if (mat == 0)
          q[(size_t)row * H_DIM + cl] = f2bf(v * 0.125f);
        else if (mat == 1)
          k[(size_t)row * H_DIM + cl] = f2bf(v);
        else
          vt[((size_t)b * H_DIM + cl) * T_SEQ + (row & (T_SEQ - 1))] = f2bf(v);
      }
    }
}

// ---------------------------------------------------------------------------
// K2: MFMA flash attention with COMPLEMENTARY Q-TILE PAIRING.
// Each block handles tiles qt_a = pa (rows [pa*16, +16)) and qt_b = 127-pa:
// combined causal extent = 16*(qt_a+qt_b)+32 = 2064 keys for EVERY block ->
// perfect static balance (grid 512, 2 equal blocks/CU).  The low tile's key
// range is a subset of the high tile's, so each K/V fragment set is loaded
// once and feeds up to 32 Q-rows (2x MFMA per byte vs the 16-row version,
// K/V L2 traffic ~270 -> ~200 MB).  Per-row j-partition across waves is
// unchanged (jt%4==w), so arithmetic order and absmax are identical.
// ---------------------------------------------------------------------------
__global__ __launch_bounds__(256) void attn_mfma(
    const short* __restrict__ q, const short* __restrict__ k,
    const short* __restrict__ vt, float* __restrict__ out) {
  __shared__ __align__(16) short pbuf[4][2048];    // per-wave: A | B
  __shared__ __align__(16) float oshare[3][2048];  // A | B
  __shared__ __align__(16) float lshare[3][512];   // A | B
  const int tid = threadIdx.x;
  const int w = tid >> 6;
  const int lane = tid & 63;
  const int n16 = lane & 15, quad = lane >> 4;
  const int b = blockIdx.x & 7;       // b == XCD slot -> K/V L2-resident
  const int pa = blockIdx.x >> 3;     // 0..63
  const int r0a = pa * 16;            // low tile rows
  const int r0b = (127 - pa) * 16;    // high tile rows

  const short* kb = k + (size_t)b * T_SEQ * H_DIM;
  const short* vb = vt + (size_t)b * H_DIM * T_SEQ;
  const short* qpa = q + ((size_t)b * T_SEQ + r0a) * H_DIM;
  const short* qpb = q + ((size_t)b * T_SEQ + r0b) * H_DIM;

  short8 aqA[2], aqB[2];
  aqA[0] = *(const short8*)(qpa + (size_t)n16 * H_DIM + quad * 8);
  aqA[1] = *(const short8*)(qpa + (size_t)n16 * H_DIM + 32 + quad * 8);
  aqB[0] = *(const short8*)(qpb + (size_t)n16 * H_DIM + quad * 8);
  aqB[1] = *(const short8*)(qpb + (size_t)n16 * H_DIM + 32 + quad * 8);

  f32x4 OA[4], OB[4];
#pragma unroll
  for (int i = 0; i < 4; ++i) {
    OA[i] = (f32x4){0.f, 0.f, 0.f, 0.f};
    OB[i] = (f32x4){0.f, 0.f, 0.f, 0.f};
  }
  float lsA[4] = {0.f, 0.f, 0.f, 0.f};
  float lsB[4] = {0.f, 0.f, 0.f, 0.f};

  const int nj = (r0b + 16 + 63) >> 6;   // j-tiles of 64 for the high tile
  const int njA = (r0a + 16 + 63) >> 6;  // j-tiles needed by the low tile

  for (int jt = w; jt < nj; jt += 4) {
    const int j0 = jt * 64;
    const bool actA = (jt < njA);  // wave-uniform

    short8 bk[4][2];
#pragma unroll
    for (int nt = 0; nt < 4; ++nt) {
      const short* kp = kb + (size_t)(j0 + nt * 16 + n16) * H_DIM + quad * 8;
      bk[nt][0] = *(const short8*)kp;
      bk[nt][1] = *(const short8*)(kp + 32);
    }

    // --- scores: high tile always, low tile while in range ---
    f32x4 sB[4];
#pragma unroll
    for (int nt = 0; nt < 4; ++nt) {
      f32x4 z = (f32x4){0.f, 0.f, 0.f, 0.f};
      z = __builtin_amdgcn_mfma_f32_16x16x32_bf16(aqB[0], bk[nt][0], z, 0, 0, 0);
      z = __builtin_amdgcn_mfma_f32_16x16x32_bf16(aqB[1], bk[nt][1], z, 0, 0, 0);
      sB[nt] = z;
    }
    f32x4 sA[4];
    if (actA) {
#pragma unroll
      for (int nt = 0; nt < 4; ++nt) {
        f32x4 z = (f32x4){0.f, 0.f, 0.f, 0.f};
        z = __builtin_amdgcn_mfma_f32_16x16x32_bf16(aqA[0], bk[nt][0], z, 0, 0, 0);
        z = __builtin_amdgcn_mfma_f32_16x16x32_bf16(aqA[1], bk[nt][1], z, 0, 0, 0);
        sA[nt] = z;
      }
    }

    // --- exp + causal mask + pack to LDS ---
    const bool fullB = (j0 + 64 <= r0b);
#pragma unroll
    for (int nt = 0; nt < 4; ++nt) {
      const int base =
          (nt >> 1) * 512 + ((((nt & 1) << 1) | (n16 >> 3)) * 128) + (n16 & 7);
#pragma unroll
      for (int r = 0; r < 4; ++r) {
        float p;
        if (fullB) {
          p = __expf(sB[nt][r]);
        } else {
          const int j = j0 + nt * 16 + n16;
          const int row = r0b + quad * 4 + r;
          p = (j <= row) ? __expf(sB[nt][r]) : 0.f;
        }
        lsB[r] += p;
        pbuf[w][1024 + base + (quad * 4 + r) * 8] = f2bf(p);
      }
    }
    if (actA) {
      const bool fullA = (j0 + 64 <= r0a);
#pragma unroll
      for (int nt = 0; nt < 4; ++nt) {
        const int base =
            (nt >> 1) * 512 + ((((nt & 1) << 1) | (n16 >> 3)) * 128) + (n16 & 7);
#pragma unroll
        for (int r = 0; r < 4; ++r) {
          float p;
          if (fullA) {
            p = __expf(sA[nt][r]);
          } else {
            const int j = j0 + nt * 16 + n16;
            const int row = r0a + quad * 4 + r;
            p = (j <= row) ? __expf(sA[nt][r]) : 0.f;
          }
          lsA[r] += p;
          pbuf[w][base + (quad * 4 + r) * 8] = f2bf(p);
        }
      }
    }

    // --- V fragments (shared by both tiles) ---
    short8 bv[4][2];
#pragma unroll
    for (int ht = 0; ht < 4; ++ht)
#pragma unroll
      for (int kh = 0; kh < 2; ++kh)
        bv[ht][kh] = *(const short8*)(vb + (size_t)(ht * 16 + n16) * T_SEQ +
                                      j0 + kh * 32 + quad * 8);

    // --- PV ---
    const short8 apB0 = *(const short8*)(&pbuf[w][1024] + lane * 8);
    const short8 apB1 = *(const short8*)(&pbuf[w][1536] + lane * 8);
#pragma unroll
    for (int ht = 0; ht < 4; ++ht) {
      OB[ht] = __builtin_amdgcn_mfma_f32_16x16x32_bf16(apB0, bv[ht][0], OB[ht], 0, 0, 0);
      OB[ht] = __builtin_amdgcn_mfma_f32_16x16x32_bf16(apB1, bv[ht][1], OB[ht], 0, 0, 0);
    }
    if (actA) {
      const short8 apA0 = *(const short8*)(&pbuf[w][0] + lane * 8);
      const short8 apA1 = *(const short8*)(&pbuf[w][512] + lane * 8);
#pragma unroll
      for (int ht = 0; ht < 4; ++ht) {
        OA[ht] = __builtin_amdgcn_mfma_f32_16x16x32_bf16(apA0, bv[ht][0], OA[ht], 0, 0, 0);
        OA[ht] = __builtin_amdgcn_mfma_f32_16x16x32_bf16(apA1, bv[ht][1], OA[ht], 0, 0, 0);
      }
    }
  }

  // --- cross-wave reduction ---
  if (w != 0) {
#pragma unroll
    for (int ht = 0; ht < 4; ++ht)
#pragma unroll
      for (int r = 0; r < 4; ++r) {
        oshare[w - 1][(ht * 4 + r) * 64 + lane] = OA[ht][r];
        oshare[w - 1][1024 + (ht * 4 + r) * 64 + lane] = OB[ht][r];
      }
#pragma unroll
    for (int r = 0; r < 4; ++r) {
      lshare[w - 1][r * 64 + lane] = lsA[r];
      lshare[w - 1][256 + r * 64 + lane] = lsB[r];
    }
  }
  __syncthreads();
  if (w == 0) {
#pragma unroll
    for (int ht = 0; ht < 4; ++ht)
#pragma unroll
      for (int r = 0; r < 4; ++r) {
        float a = OA[ht][r], bb = OB[ht][r];
#pragma unroll
        for (int ow = 0; ow < 3; ++ow) {
          a += oshare[ow][(ht * 4 + r) * 64 + lane];
          bb += oshare[ow][1024 + (ht * 4 + r) * 64 + lane];
        }
        OA[ht][r] = a;
        OB[ht][r] = bb;
      }
#pragma unroll
    for (int r = 0; r < 4; ++r) {
      float va = lsA[r], vb2 = lsB[r];
#pragma unroll
      for (int ow = 0; ow < 3; ++ow) {
        va += lshare[ow][r * 64 + lane];
        vb2 += lshare[ow][256 + r * 64 + lane];
      }
      va += __shfl_xor(va, 1);
      va += __shfl_xor(va, 2);
      va += __shfl_xor(va, 4);
      va += __shfl_xor(va, 8);
      vb2 += __shfl_xor(vb2, 1);
      vb2 += __shfl_xor(vb2, 2);
      vb2 += __shfl_xor(vb2, 4);
      vb2 += __shfl_xor(vb2, 8);
      lsA[r] = va;
      lsB[r] = vb2;
    }
#pragma unroll
    for (int ht = 0; ht < 4; ++ht)
#pragma unroll
      for (int r = 0; r < 4; ++r) {
        out[((size_t)b * T_SEQ + r0a + quad * 4 + r) * H_DIM + ht * 16 + n16] =
            OA[ht][r] / lsA[r];
        out[((size_t)b * T_SEQ + r0b + quad * 4 + r) * H_DIM + ht * 16 + n16] =
            OB[ht][r] / lsB[r];
      }
  }
}

extern "C" void kernel_launch(void* const* d_in, const int* in_sizes, int n_in,
                              void* d_out, int out_size, void* d_ws,
                              size_t ws_size, hipStream_t stream) {
  const float* x = (const float*)d_in[0];
  const float* Wq = (const float*)d_in[1];
  const float* Wk = (const float*)d_in[2];
  const float* Wv = (const float*)d_in[3];

  char* ws = (char*)d_ws;
  short* Wt = (short*)ws;                       // 384 KB (fragment-linear)
  short* q = (short*)(ws + 3 * 64 * 1024 * 2);  // 2 MB each
  short* kk = (short*)(ws + 3 * 64 * 1024 * 2 + 2097152);
  short* vt = (short*)(ws + 3 * 64 * 1024 * 2 + 2 * 2097152);

  w_prep<<<96, 256, 0, stream>>>(Wq, Wk, Wv, Wt);
  qkv_gemm<<<NROW / 32, 256, 0, stream>>>(x, Wt, q, kk, vt);
  attn_mfma<<<B_DIM * (T_SEQ / 32), 256, 0, stream>>>(q, kk, vt, (float*)d_out);
}